// Round 13
// baseline (226.086 us; speedup 1.0000x reference)
//
#include <hip/hip_runtime.h>
#include <stdint.h>

// FFN: x[16384,1024] -> relu(x@W1^T+b1)[16384,4096] -> q_e4m3 -> @W2^T+b2 -> q_e5m10
// Round 15: fold the x->f16 cast into GEMM1's A-staging (kills the 96MB x
// pre-pass leg, ~16us of pure HBM traffic). A-stage is now per-thread
// {4x coalesced dwordx4 fp32 loads -> RNE casts -> 4x swizzled ds_write_b64};
// layout keeps 16 consecutive lanes on 256 contiguous bytes (not r5's
// scattered per-lane pattern) and writes land at the read-side swizzle slot
// (slot^(row&7), row&7 thread-invariant). lgkmcnt(0) added before the stage
// barrier. B stays gl16 from w1h. Values bit-identical (same RNE cast, same
// MFMA sequence). Prepass now w1+w2 only. GEMM structure = r12/r10 best:
// 128x256 tile, 8 waves 64x64, single-buffer LDS, 2 blocks/CU, barrier-light
// loop, no setprio, sched_barrier(0) pin, XCD swizzle, MX-fp8 GEMM2.

#define M_TOT 16384
#define D_DIM 1024
#define H_DIM 4096

typedef _Float16 f16x8 __attribute__((ext_vector_type(8)));
typedef _Float16 f16x4 __attribute__((ext_vector_type(4)));
typedef float f32x4 __attribute__((ext_vector_type(4)));
typedef int i32x4 __attribute__((ext_vector_type(4)));
typedef int i32x8 __attribute__((ext_vector_type(8)));

// global -> LDS direct copy, 16B per lane. LDS dest = wave-uniform base + lane*16.
__device__ __forceinline__ void gl16(const void* g, void* l) {
    __builtin_amdgcn_global_load_lds(
        (const __attribute__((address_space(1))) unsigned int*)(uintptr_t)g,
        (__attribute__((address_space(3))) unsigned int*)(unsigned int)(uintptr_t)l,
        16, 0, 0);
}

// positive-input e4m3 quantize (post-relu), division-free, RNE. Returns the
// quantized VALUE as f16 (exactly representable).
__device__ __forceinline__ _Float16 q_e4m3_pos(float v) {
    uint32_t t = __float_as_uint(v);
    uint32_t tn = (t + 0x7ffffu + ((t >> 20) & 1u)) & 0xfff00000u;
    float qn = __uint_as_float(tn);
    float qs = rintf(v * 512.0f) * 0.001953125f;
    return (_Float16)(v < 0.015625f ? qs : qn);
}

// ---- fused pre-pass (w1, w2 only; x is cast inside GEMM1 now):
//   blocks [0,4096)    : w1 fp32 -> f16 (RNE), x4 vectorized
//   blocks [4096,8192) : w2 fp32 -> e4m3 BYTES via HW cvt (RNE, OCP grid)
__global__ __launch_bounds__(256) void prepass_kernel(
    const float* __restrict__ w1, _Float16* __restrict__ w1h,
    const float* __restrict__ w2, uint32_t* __restrict__ wq)
{
    const int b = blockIdx.x;
    if (b < 4096) {
        int i = b * 256 + threadIdx.x;            // 1,048,576 quads exactly
        float4 v = reinterpret_cast<const float4*>(w1)[i];
        f16x4 hv = {(_Float16)v.x, (_Float16)v.y, (_Float16)v.z, (_Float16)v.w};
        reinterpret_cast<f16x4*>(w1h)[i] = hv;
    } else {
        int i = (b - 4096) * 256 + threadIdx.x;   // 1,048,576 quads exactly
        float4 v = reinterpret_cast<const float4*>(w2)[i];
        uint32_t r = __builtin_amdgcn_cvt_pk_fp8_f32(v.x, v.y, 0, false);
        r = __builtin_amdgcn_cvt_pk_fp8_f32(v.z, v.w, r, true);
        wq[i] = r;
    }
}

// ---- GEMM1: h=relu(x@w1h^T+b1), q_e4m3, store BYTES. 128x256 BK=64. ----
// A read as fp32 from x, cast to f16 in the staging path. 8 waves (2M x 4N)
// of 64x64; acc=64 regs; single-buffer staging in a 64KB LDS block (epilogue
// transpose reuses it). 2 blocks/CU.
__global__ __launch_bounds__(512, 4) void gemm1_f16(
    const float* __restrict__ Af, const _Float16* __restrict__ B,
    const float* __restrict__ bias, uint8_t* __restrict__ Cq)
{
    constexpr int K = D_DIM;   // 1024
    constexpr int N = H_DIM;   // 4096 (bytes per out row)
    __shared__ __align__(16) _Float16 smem[32768];   // 64 KiB
    _Float16* sA = smem;            // [128][64] = 8192 f16 (16KB)
    _Float16* sB = smem + 8192;     // [256][64] = 16384 f16 (32KB)

    const int tid  = threadIdx.x;
    const int lane = tid & 63;
    const int w    = tid >> 6;
    const int wr   = w >> 2, wc = w & 3;   // per-wave C: 64 rows x 64 cols
    const int fr   = lane & 15, kq = lane >> 4;

    constexpr int NBX = N / 256;               // 16
    constexpr int NWG = (M_TOT / 128) * NBX;   // 2048
    constexpr int CPX = NWG / 8;
    int bid = blockIdx.y * NBX + blockIdx.x;
    bid = (bid & 7) * CPX + (bid >> 3);
    const int n0 = (bid % NBX) * 256;
    const int m0 = (bid / NBX) * 128;

    // B staging (unchanged): round = 64 rows x 128B; 4 rounds via gl16.
    const int srow = tid >> 3;
    const int sseg = (tid & 7) ^ (srow & 7);
    const _Float16* gB = B + (size_t)(n0 + srow) * K + sseg * 8;
    const int ldsw = w * 512;                        // f16 per wave per round
    const size_t R1 = (size_t)64 * K, R2 = (size_t)128 * K, R3 = (size_t)192 * K;

    // A staging (fp32->f16 in-kernel): round r covers rows [32r,32r+32).
    // thread -> row = 32r + (tid>>4), fp32 cols (tid&15)*4..+4 (16B, lanes
    // consecutive => 256B contiguous per 16 lanes). LDS dest slot =
    // ((tid&15)>>1) ^ (row&7); row&7 == (tid>>4)&7 for all r.
    const float* pAf = Af + (size_t)(m0 + (tid >> 4)) * K + (tid & 15) * 4;
    const int ldsAb = (tid >> 4) * 128
                    + ((((tid & 15) >> 1) ^ ((tid >> 4) & 7)) * 16)
                    + (tid & 1) * 8;

    const int xorv = fr & 7;
    const int cA0 = (kq ^ xorv) * 8;
    const int cA1 = ((kq + 4) ^ xorv) * 8;
    const int aRow = wr * 64 + fr;
    const int bRow = wc * 64 + fr;

    f32x4 acc[4][4];
#pragma unroll
    for (int i = 0; i < 4; i++)
#pragma unroll
        for (int j = 0; j < 4; j++) acc[i][j] = (f32x4){0.f, 0.f, 0.f, 0.f};

    f16x8 bfr[4][2];
    constexpr int NK = K / 64;   // 16

    // prologue: stage tile 0 (B via gl16; A via load+cvt+ds_write).
    gl16(gB,      sB + ldsw);
    gl16(gB + R1, sB + 4096 + ldsw);
    gl16(gB + R2, sB + 8192 + ldsw);
    gl16(gB + R3, sB + 12288 + ldsw);
    {
        float4 av[4];
#pragma unroll
        for (int r = 0; r < 4; r++)
            av[r] = *(const float4*)(pAf + (size_t)(32 * r) * K);
#pragma unroll
        for (int r = 0; r < 4; r++) {
            f16x4 h = {(_Float16)av[r].x, (_Float16)av[r].y,
                       (_Float16)av[r].z, (_Float16)av[r].w};
            *(f16x4*)((char*)sA + ldsAb + r * 4096) = h;
        }
    }
    asm volatile("s_waitcnt vmcnt(0) lgkmcnt(0)" ::: "memory");
    __builtin_amdgcn_s_barrier();
    asm volatile("" ::: "memory");

    for (int t = 0; t < NK; ++t) {
        // ---- compute tile t from the single buffer ----
#pragma unroll
        for (int j = 0; j < 4; j++) {
            const _Float16* rb = sB + (bRow + j * 16) * 64;
            bfr[j][0] = *(const f16x8*)(rb + cA0);
            bfr[j][1] = *(const f16x8*)(rb + cA1);
        }
        f16x8 afr[2][2];
        {
            const _Float16* ra = sA + aRow * 64;
            afr[0][0] = *(const f16x8*)(ra + cA0);
            afr[0][1] = *(const f16x8*)(ra + cA1);
        }
#pragma unroll
        for (int i = 0; i < 4; ++i) {
            const int cur = i & 1, nxt = cur ^ 1;
            if (i < 3) {
                const _Float16* ra = sA + (aRow + (i + 1) * 16) * 64;
                afr[nxt][0] = *(const f16x8*)(ra + cA0);
                afr[nxt][1] = *(const f16x8*)(ra + cA1);
            }
            __builtin_amdgcn_sched_barrier(0);
#pragma unroll
            for (int j = 0; j < 4; j++) {
                acc[i][j] = __builtin_amdgcn_mfma_f32_16x16x32_f16(
                    afr[cur][0], bfr[j][0], acc[i][j], 0, 0, 0);
                acc[i][j] = __builtin_amdgcn_mfma_f32_16x16x32_f16(
                    afr[cur][1], bfr[j][1], acc[i][j], 0, 0, 0);
            }
        }
        // all waves done reading tile t
        asm volatile("" ::: "memory");
        __builtin_amdgcn_s_barrier();
        asm volatile("" ::: "memory");

        if (t + 1 < NK) {
            // stage tile t+1; drain is dead time for THIS block, covered by
            // the co-resident partner block's compute (r10-proven).
            const int t64n = (t + 1) * 64;
            gl16(gB + t64n,      sB + ldsw);
            gl16(gB + t64n + R1, sB + 4096 + ldsw);
            gl16(gB + t64n + R2, sB + 8192 + ldsw);
            gl16(gB + t64n + R3, sB + 12288 + ldsw);
            float4 av[4];
#pragma unroll
            for (int r = 0; r < 4; r++)
                av[r] = *(const float4*)(pAf + (size_t)(32 * r) * K + t64n);
#pragma unroll
            for (int r = 0; r < 4; r++) {
                f16x4 h = {(_Float16)av[r].x, (_Float16)av[r].y,
                           (_Float16)av[r].z, (_Float16)av[r].w};
                *(f16x4*)((char*)sA + ldsAb + r * 4096) = h;
            }
            asm volatile("s_waitcnt vmcnt(0) lgkmcnt(0)" ::: "memory");
            __builtin_amdgcn_s_barrier();
            asm volatile("" ::: "memory");
        }
    }

    // epilogue: +bias, relu, q_e4m3 (f16 value) -> swizzled 64KB LDS tile
    // [128][256] f16 -> read f16x8, cvt to e4m3 bytes, coalesced 16B stores.
    const int col0 = n0 + wc * 64 + fr;
    float bv[4];
#pragma unroll
    for (int j = 0; j < 4; j++) bv[j] = bias[col0 + j * 16];
    const int sub = (fr & 7) * 2;
    const int slotbase = wc * 8 + (fr >> 3);
    const int rowbase = wr * 64 + kq * 4;
#pragma unroll
    for (int i = 0; i < 4; i++) {
        const int trow0 = rowbase + i * 16;
#pragma unroll
        for (int r = 0; r < 4; r++) {
            const int trow = trow0 + r;
            const int swz = ((kq & 1) * 4 + r) ^ (kq >> 1);  // == (trow&7)^((trow>>3)&1)
#pragma unroll
            for (int j = 0; j < 4; j++) {
                float v = fmaxf(acc[i][j][r] + bv[j], 0.0f);
                _Float16 q = q_e4m3_pos(v);
                int byte = trow * 512 + (((slotbase + j * 2) ^ swz) << 4) + sub;
                *(_Float16*)((char*)smem + byte) = q;
            }
        }
    }
    __syncthreads();
#pragma unroll
    for (int cch = 0; cch < 8; cch++) {
        int flat = cch * 512 + tid;          // 16B-chunk index, 4096 total
        int row  = flat >> 5;                // 0..127
        int slot = flat & 31;
        int swz  = (row & 7) ^ ((row >> 3) & 1);
        f16x8 v8 = *(const f16x8*)((char*)smem + row * 512 + ((slot ^ swz) << 4));
        uint32_t u0 = __builtin_amdgcn_cvt_pk_fp8_f32((float)v8[0], (float)v8[1], 0, false);
        u0 = __builtin_amdgcn_cvt_pk_fp8_f32((float)v8[2], (float)v8[3], u0, true);
        uint32_t u1 = __builtin_amdgcn_cvt_pk_fp8_f32((float)v8[4], (float)v8[5], 0, false);
        u1 = __builtin_amdgcn_cvt_pk_fp8_f32((float)v8[6], (float)v8[7], u1, true);
        uint2 u = {u0, u1};
        *(uint2*)(Cq + (size_t)(m0 + row) * N + n0 + slot * 8) = u;
    }
}

// ---- GEMM2: out = hq @ wq^T + b2q (MX-fp8, unit scales), q_e5m10, fp32 out ----
// 128x256 tile, BK=128 bytes, 8 waves of 64x64; acc=64; 48KB single-buffer LDS;
// 2 blocks/CU. Grid (4,128) = 512 wg. (byte-identical to round 14)
__global__ __launch_bounds__(512, 4) void gemm2_fp8(
    const uint8_t* __restrict__ A, const uint8_t* __restrict__ B,
    const float* __restrict__ b2, float* __restrict__ C)
{
    constexpr int Kb = H_DIM;  // 4096 bytes per row
    constexpr int N  = D_DIM;  // 1024
    __shared__ __align__(16) uint8_t smem[49152];    // 48 KiB
    uint8_t* sA = smem;            // [128][128B] = 16KB
    uint8_t* sB = smem + 16384;    // [256][128B] = 32KB

    const int tid  = threadIdx.x;
    const int lane = tid & 63;
    const int w    = tid >> 6;
    const int wr   = w >> 2, wc = w & 3;   // per-wave C: 64 rows x 64 cols
    const int fr   = lane & 15, kq = lane >> 4;

    constexpr int NBX = N / 256;               // 4
    constexpr int NWG = (M_TOT / 128) * NBX;   // 512
    constexpr int CPX = NWG / 8;
    int bid = blockIdx.y * NBX + blockIdx.x;
    bid = (bid & 7) * CPX + (bid >> 3);
    const int n0 = (bid % NBX) * 256;
    const int m0 = (bid / NBX) * 128;

    const int srow = tid >> 3;
    const int sseg = (tid & 7) ^ (srow & 7);     // 16B-slot pre-swizzle
    const uint8_t* gA = A + (size_t)(m0 + srow) * Kb + sseg * 16;
    const uint8_t* gB = B + (size_t)(n0 + srow) * Kb + sseg * 16;
    const int ldsw = w * 1024;                   // bytes per wave per round
    const size_t R1 = (size_t)64 * Kb, R2 = (size_t)128 * Kb, R3 = (size_t)192 * Kb;

    const int xorv = fr & 7;
    const int sO0 = ((2 * kq) ^ xorv) * 16;
    const int sO1 = ((2 * kq + 1) ^ xorv) * 16;
    const int aRowB = (wr * 64 + fr) * 128;
    const int bRowB = (wc * 64 + fr) * 128;

    f32x4 acc[4][4];
#pragma unroll
    for (int i = 0; i < 4; i++)
#pragma unroll
        for (int j = 0; j < 4; j++) acc[i][j] = (f32x4){0.f, 0.f, 0.f, 0.f};

    i32x8 bfr[4];
    constexpr int NK = Kb / 128;   // 32
    constexpr uint32_t SC1 = 0x7f7f7f7fu;   // e8m0 unit scale in every byte

    gl16(gB,      sB + ldsw);
    gl16(gB + R1, sB + 8192 + ldsw);
    gl16(gB + R2, sB + 16384 + ldsw);
    gl16(gB + R3, sB + 24576 + ldsw);
    gl16(gA,      sA + ldsw);
    gl16(gA + R1, sA + 8192 + ldsw);
    asm volatile("s_waitcnt vmcnt(0)" ::: "memory");
    __builtin_amdgcn_s_barrier();
    asm volatile("" ::: "memory");

    for (int t = 0; t < NK; ++t) {
        // ---- compute tile t ----
#pragma unroll
        for (int j = 0; j < 4; j++) {
            const uint8_t* rb = sB + bRowB + j * 2048;
            i32x4 lo = *(const i32x4*)(rb + sO0);
            i32x4 hi = *(const i32x4*)(rb + sO1);
            bfr[j] = (i32x8){lo.x, lo.y, lo.z, lo.w, hi.x, hi.y, hi.z, hi.w};
        }
#pragma unroll
        for (int i = 0; i < 4; ++i) {
            const uint8_t* ra = sA + aRowB + i * 2048;
            i32x4 lo = *(const i32x4*)(ra + sO0);
            i32x4 hi = *(const i32x4*)(ra + sO1);
            i32x8 af = (i32x8){lo.x, lo.y, lo.z, lo.w, hi.x, hi.y, hi.z, hi.w};
            __builtin_amdgcn_sched_barrier(0);
#pragma unroll
            for (int j = 0; j < 4; j++) {
                acc[i][j] = __builtin_amdgcn_mfma_scale_f32_16x16x128_f8f6f4(
                    af, bfr[j], acc[i][j],
                    0, 0,            // cbsz=FP8, blgp=FP8
                    0, SC1,          // opsel_a, scale_a (1.0)
                    0, SC1);         // opsel_b, scale_b (1.0)
            }
        }
        asm volatile("" ::: "memory");
        __builtin_amdgcn_s_barrier();
        asm volatile("" ::: "memory");

        if (t + 1 < NK) {
            const uint8_t* gAn = gA + (size_t)(t + 1) * 128;
            const uint8_t* gBn = gB + (size_t)(t + 1) * 128;
            gl16(gBn,      sB + ldsw);
            gl16(gBn + R1, sB + 8192 + ldsw);
            gl16(gBn + R2, sB + 16384 + ldsw);
            gl16(gBn + R3, sB + 24576 + ldsw);
            gl16(gAn,      sA + ldsw);
            gl16(gAn + R1, sA + 8192 + ldsw);
            asm volatile("s_waitcnt vmcnt(0)" ::: "memory");
            __builtin_amdgcn_s_barrier();
            asm volatile("" ::: "memory");
        }
    }

    // epilogue: + q_e5m10(b2), quantize e5m10 (f16 RNE roundtrip), store fp32
    const int col0 = n0 + wc * 64 + fr;
    const int row0 = m0 + wr * 64 + kq * 4;
#pragma unroll
    for (int j = 0; j < 4; j++) {
        const float bq = (float)(_Float16)b2[col0 + j * 16];
#pragma unroll
        for (int i = 0; i < 4; i++) {
            size_t base = (size_t)(row0 + i * 16) * N + (col0 + j * 16);
#pragma unroll
            for (int r = 0; r < 4; r++) {
                float v = acc[i][j][r] + bq;
                C[base + (size_t)r * N] = (float)(_Float16)v;
            }
        }
    }
}

extern "C" void kernel_launch(void* const* d_in, const int* in_sizes, int n_in,
                              void* d_out, int out_size, void* d_ws, size_t ws_size,
                              hipStream_t stream) {
    const float* x  = (const float*)d_in[0];   // [16384,1024]
    const float* w1 = (const float*)d_in[1];   // [4096,1024]
    const float* b1 = (const float*)d_in[2];   // [4096]
    const float* w2 = (const float*)d_in[3];   // [1024,4096]
    const float* b2 = (const float*)d_in[4];   // [1024]
    float* out = (float*)d_out;

    // workspace layout (bytes):
    // hq  e4m3 bytes [16384,4096] :  67,108,864
    // w1h f16 [4096,1024]         :   8,388,608
    // wq  e4m3 bytes [1024,4096]  :   4,194,304
    const size_t need = 67108864ull + 8388608ull + 4194304ull;
    if (ws_size < need) return;  // fail visibly (output stays zero)

    char* ws = (char*)d_ws;
    uint8_t*  hq  = (uint8_t*)ws;
    _Float16* w1h = (_Float16*)(ws + 67108864ull);
    uint8_t*  wq  = (uint8_t*)(w1h + 4194304);

    // fused pre-pass: w1->f16, w2->e4m3 bytes (x is cast inside GEMM1)
    prepass_kernel<<<8192, 256, 0, stream>>>(w1, w1h, w2, (uint32_t*)wq);

    // GEMM1: M=16384, N=4096, K=1024 -> grid (16,128) = 2048 wg, 2 blocks/CU
    gemm1_f16<<<dim3(H_DIM / 256, M_TOT / 128), 512, 0, stream>>>(x, w1h, b1, hq);
    // GEMM2: M=16384, N=1024, K=4096 bytes -> grid (4,128) = 512 wg, 2 blocks/CU
    gemm2_fp8<<<dim3(D_DIM / 256, M_TOT / 128), 512, 0, stream>>>(hq, wq, b2, out);
}